// Round 7
// baseline (389.383 us; speedup 1.0000x reference)
//
#include <hip/hip_runtime.h>
#include <hip/hip_bf16.h>
#include <cstdint>
#include <cstddef>

#define TOK   8192
#define DIN   4096
#define DOUT  4096
#define RANK  16
#define KE    4160   // DIN + 16 (loraB) + 1 (bias) + 47 pad -> 65 * 64
#define NKT64 (KE / 64)

#define BM 256
#define BN 256

// prep_fused block ranges
#define PXB 512                    // prep_x blocks
#define DQB 8192                   // dequant blocks
#define TLB 16                     // tail blocks

typedef __attribute__((ext_vector_type(8))) short bf16x8;
typedef __attribute__((ext_vector_type(16))) float f32x16;
typedef __attribute__((ext_vector_type(8))) unsigned short u16x8;

__device__ __constant__ float NF4_CODE_D[16] = {
    -1.0f, -0.6961928009986877f, -0.5250730514526367f, -0.39491748809814453f,
    -0.28444138169288635f, -0.18477343022823334f, -0.09105003625154495f, 0.0f,
    0.07958029955625534f, 0.16093020141124725f, 0.24611230194568634f,
    0.33791524171829224f, 0.44070982933044434f, 0.5626170039176941f,
    0.7229568362236023f, 1.0f};

__device__ __forceinline__ unsigned short f2bf(float f) {
    union { float f; unsigned u; } v; v.f = f;
    unsigned u = v.u;
    unsigned r = (u + 0x7FFFu + ((u >> 16) & 1u)) >> 16;  // round-nearest-even
    return (unsigned short)r;
}

__device__ __forceinline__ void async_copy16(const void* g, void* l) {
    __builtin_amdgcn_global_load_lds(
        (const __attribute__((address_space(1))) void*)g,
        (__attribute__((address_space(3))) void*)l,
        16, 0, 0);
}

// ---------------------------------------------------------------------------
// Fused prep: one launch, three block ranges.
//  [0, PXB):        x -> bf16 xe[TOK][KE]; cols [4096,4112)=4*(x@lora_A);
//                   col 4112 = 1.0; rest 0.
//  [PXB, PXB+DQB):  NF4 dequant -> we[DOUT][KE] cols [0,4096)
//  [PXB+DQB, +TLB): we tail cols: loraB^T, bias, zeros
// ---------------------------------------------------------------------------
__global__ __launch_bounds__(256) void prep_fused(
        const float* __restrict__ x, const float* __restrict__ lora_A,
        const int* __restrict__ codes, const float* __restrict__ absmax,
        const float* __restrict__ bias, const float* __restrict__ lora_B,
        unsigned short* __restrict__ xe, unsigned short* __restrict__ we) {
    __shared__ float tab[16];
    const int bid = blockIdx.x;
    const int tid = threadIdx.x;

    if (bid < PXB) {
        // ---- prep_x ----
        const int l = tid & 63;
        const int w = tid >> 6;
        const int t0 = bid * 16 + w * 4;

        float p[4][16];
#pragma unroll
        for (int a = 0; a < 4; ++a)
#pragma unroll
            for (int r = 0; r < 16; ++r) p[a][r] = 0.f;

        for (int it = 0; it < 16; ++it) {
            const int kb = it * 256 + l * 4;
            float4 xv[4];
#pragma unroll
            for (int a = 0; a < 4; ++a)
                xv[a] = *(const float4*)(x + (size_t)(t0 + a) * DIN + kb);
#pragma unroll
            for (int a = 0; a < 4; ++a) {
                ushort4 s;
                s.x = f2bf(xv[a].x); s.y = f2bf(xv[a].y);
                s.z = f2bf(xv[a].z); s.w = f2bf(xv[a].w);
                *(ushort4*)(xe + (size_t)(t0 + a) * KE + kb) = s;
            }
#pragma unroll
            for (int j = 0; j < 4; ++j) {
                const float4* ap = (const float4*)(lora_A + (size_t)(kb + j) * RANK);
                const float4 a0 = ap[0], a1 = ap[1], a2 = ap[2], a3 = ap[3];
                const float av[16] = {a0.x, a0.y, a0.z, a0.w, a1.x, a1.y, a1.z, a1.w,
                                      a2.x, a2.y, a2.z, a2.w, a3.x, a3.y, a3.z, a3.w};
#pragma unroll
                for (int a = 0; a < 4; ++a) {
                    const float xs = (j == 0) ? xv[a].x : (j == 1) ? xv[a].y
                                    : (j == 2) ? xv[a].z : xv[a].w;
#pragma unroll
                    for (int r = 0; r < 16; ++r) p[a][r] += xs * av[r];
                }
            }
        }

#pragma unroll
        for (int a = 0; a < 4; ++a) {
#pragma unroll
            for (int r = 0; r < 16; ++r) {
                float v = p[a][r];
#pragma unroll
                for (int off = 32; off > 0; off >>= 1) v += __shfl_xor(v, off, 64);
                if (l == r)
                    xe[(size_t)(t0 + a) * KE + DIN + r] = f2bf(4.0f * v);  // SCALING=4
            }
            if (l >= 16)  // cols 4112..4159: bias-one then zeros
                xe[(size_t)(t0 + a) * KE + DIN + l] =
                    (l == 16) ? (unsigned short)0x3F80u : (unsigned short)0u;
        }
    } else if (bid < PXB + DQB) {
        // ---- dequant_w ----
        if (tid < 16) tab[tid] = NF4_CODE_D[tid];
        __syncthreads();
        const size_t t = (size_t)(bid - PXB) * 256 + tid;
        const size_t base = t * 8;
        const int o = (int)(base >> 12);          // / DIN
        const int k = (int)(base & (DIN - 1));
        const float am = absmax[base >> 6];
        const int4 c0 = *(const int4*)(codes + base);
        const int4 c1 = *(const int4*)(codes + base + 4);
        u16x8 ov;
        ov[0] = f2bf(tab[c0.x] * am);
        ov[1] = f2bf(tab[c0.y] * am);
        ov[2] = f2bf(tab[c0.z] * am);
        ov[3] = f2bf(tab[c0.w] * am);
        ov[4] = f2bf(tab[c1.x] * am);
        ov[5] = f2bf(tab[c1.y] * am);
        ov[6] = f2bf(tab[c1.z] * am);
        ov[7] = f2bf(tab[c1.w] * am);
        *(u16x8*)(we + (size_t)o * KE + k) = ov;
    } else {
        // ---- fill we tail ----
        const int o = (bid - PXB - DQB) * 256 + tid;
        unsigned short* dst = we + (size_t)o * KE + DIN;
#pragma unroll
        for (int r = 0; r < RANK; ++r) dst[r] = f2bf(lora_B[(size_t)r * DOUT + o]);
        dst[16] = f2bf(bias[o]);
#pragma unroll
        for (int r = 17; r < 64; ++r) dst[r] = 0;
    }
}

// ---------------------------------------------------------------------------
// Kernel 2: C[t,o] = sum_k A[t,k]*B[o,k]  (K-major bf16, K=KE)
// R7 = R4 schedule (one-phase-ahead ds_read pipelining, counted lgkm via
// compiler, staggered staging A/B/A/B, 2 barriers + 2 vmcnt(2) per K64-tile)
// with:
//   * MFMA switched to 32x32x16 bf16 (higher matrix-pipe rate; identical LDS
//     bytes and fragment-register footprint). Per wave-tile 128x64:
//     4 m-tiles x 2 n-tiles, acc = 8 x f32x16. Per K32-slice: A-frags
//     aX[mt*2+kk] (8 for m0..3), B-frags bX[nt*2+kk] (4). Phase = 8 MFMA.
//   * XCD-aware block swizzle (512 blocks, 512%8==0 -> bijective).
// Fragment layouts (guide-verified): A row = l&31, k = (l>>5)*8+j;
// B col = l&31, same k; C/D col = l&31, row = (reg&3)+8*(reg>>2)+4*(l>>5).
// LDS swizzle mask unchanged: byte bits[9:7] (= row[3:1] = l[3:1]) -> [6:4].
//
// vmcnt ledger (per wave; 2 loads per stageA/stageB) — identical to R4:
//   entering ph0(t): outstanding = {A(t,1),B(t,1)} = 4
//   ph0 stages A(t+1,0) -> 6; ph1 vmcnt(2) retires A(t,1),B(t,1) = S1(t)
//   ph1 stages B(t+1,0) -> 4+... ph2 stages A(t+1,1);
//   ph3-top outstanding {A(t+1,0),B(t+1,0),A(t+1,1)} = 6 -> vmcnt(2)
//   retires S0(t+1); leaves {A(t+1,1)} and ph3 stages B(t+1,1) -> invariant.
//   Last tile: ph1 vmcnt(0).
// ---------------------------------------------------------------------------
__global__ __launch_bounds__(512, 2) void gemm_bt(const unsigned short* __restrict__ A,
                                                  const unsigned short* __restrict__ B,
                                                  float* __restrict__ C) {
    __shared__ __attribute__((aligned(1024))) char smem[4 * 32768];  // 128 KiB

    const int tid = threadIdx.x;
    const int l = tid & 63;
    const int w = tid >> 6;
    const int wm = w >> 2;      // 0..1
    const int wn = w & 3;       // 0..3

    // XCD-aware bijective swizzle: 512 workgroups, 8 XCDs, 64 per XCD chunk
    const int swz = (blockIdx.x & 7) * 64 + (blockIdx.x >> 3);
    const int tm = swz >> 4;     // 32 row tiles
    const int tn = swz & 15;     // 16 col tiles
    const int rowBase = tm * BM;
    const int colBase = tn * BN;

    // staging coords (pre-swizzled global source; linear LDS dest)
    int srow[2], scolb[2], loffs[2];
#pragma unroll
    for (int g = 0; g < 2; ++g) {
        const int loff = g * 8192 + tid * 16;               // linear LDS byte
        const int soff = loff ^ (((loff >> 7) & 7) << 4);   // involution
        loffs[g] = loff;
        srow[g] = soff >> 6;          // row of [256][32] bf16 slice
        scolb[g] = soff & 63;         // byte within 64B row
    }

    auto stageA = [&](int tt, int kh, int slot) {
        char* dst = smem + slot * 32768;
        const int k0 = tt * 64 + kh * 32;
#pragma unroll
        for (int g = 0; g < 2; ++g)
            async_copy16((const char*)A + ((size_t)(rowBase + srow[g]) * KE + k0) * 2 + scolb[g],
                         dst + loffs[g]);
    };
    auto stageB = [&](int tt, int kh, int slot) {
        char* dst = smem + slot * 32768 + 16384;
        const int k0 = tt * 64 + kh * 32;
#pragma unroll
        for (int g = 0; g < 2; ++g)
            async_copy16((const char*)B + ((size_t)(colBase + srow[g]) * KE + k0) * 2 + scolb[g],
                         dst + loffs[g]);
    };

    // 32x32 fragment read offsets within a 16 KiB slice ([256][32] bf16,
    // 64B rows, XOR-swizzled bits[9:7]->[6:4]; mask = l[3:1]<<4)
    const int r32 = l & 31;
    const int h32 = (l >> 5) & 1;
    const int lmask = ((l >> 1) & 7) << 4;
    int aoffs[4][2], boffs[2][2];
#pragma unroll
    for (int mt = 0; mt < 4; ++mt)
#pragma unroll
        for (int kk = 0; kk < 2; ++kk)
            aoffs[mt][kk] = (((wm * 128 + mt * 32 + r32) * 64) + kk * 32 + h32 * 16) ^ lmask;
#pragma unroll
    for (int nt = 0; nt < 2; ++nt)
#pragma unroll
        for (int kk = 0; kk < 2; ++kk)
            boffs[nt][kk] = 16384 + ((((wn * 64 + nt * 32 + r32) * 64) + kk * 32 + h32 * 16) ^ lmask);

    f32x16 acc[4][2];
#pragma unroll
    for (int mt = 0; mt < 4; ++mt)
#pragma unroll
        for (int nt = 0; nt < 2; ++nt)
#pragma unroll
            for (int r = 0; r < 16; ++r) acc[mt][nt][r] = 0.f;

    bf16x8 aLo[4], aHi[4], aLo2[4], aHi2[4], bCur[4], bNxt[4];
    // index: aLo[mt*2+kk] mt in {0,1}; aHi -> mt in {2,3}; bCur[nt*2+kk]

    // prologue: tile 0 slices into slots 0,1; publish S0(0); preload ph0 regs
    stageA(0, 0, 0); stageB(0, 0, 0);
    stageA(0, 1, 1); stageB(0, 1, 1);
    asm volatile("s_waitcnt vmcnt(4)" ::: "memory");
    __builtin_amdgcn_s_barrier();
    {
        const char* S0 = smem;  // slot 0
#pragma unroll
        for (int nt = 0; nt < 2; ++nt)
#pragma unroll
            for (int kk = 0; kk < 2; ++kk)
                bCur[nt * 2 + kk] = *(const bf16x8*)(S0 + boffs[nt][kk]);
#pragma unroll
        for (int mt = 0; mt < 2; ++mt)
#pragma unroll
            for (int kk = 0; kk < 2; ++kk)
                aLo[mt * 2 + kk] = *(const bf16x8*)(S0 + aoffs[mt][kk]);
    }

    for (int t = 0; t < NKT64; ++t) {
        const char* S0 = smem + ((2 * t) & 3) * 32768;       // slice (t,k0)
        const char* S1 = smem + ((2 * t + 1) & 3) * 32768;   // slice (t,k1)
        const char* Sn = smem + ((2 * t + 2) & 3) * 32768;   // slice (t+1,k0)
        const int d0 = (2 * t + 2) & 3, d1 = (2 * t + 3) & 3;
        const bool more = (t + 1 < NKT64);

        // ---- phase 0: MFMA(m0,m1 x bCur); read-ahead aHi(S0); stage A(t+1,0)
#pragma unroll
        for (int mt = 0; mt < 2; ++mt)
#pragma unroll
            for (int kk = 0; kk < 2; ++kk)
                aHi[mt * 2 + kk] = *(const bf16x8*)(S0 + aoffs[2 + mt][kk]);
        if (more) stageA(t + 1, 0, d0);
        __builtin_amdgcn_sched_barrier(0);
        __builtin_amdgcn_s_setprio(1);
#pragma unroll
        for (int kk = 0; kk < 2; ++kk)
#pragma unroll
            for (int mt = 0; mt < 2; ++mt)
#pragma unroll
                for (int nt = 0; nt < 2; ++nt)
                    acc[mt][nt] = __builtin_amdgcn_mfma_f32_32x32x16_bf16(
                        aLo[mt * 2 + kk], bCur[nt * 2 + kk], acc[mt][nt], 0, 0, 0);
        __builtin_amdgcn_s_setprio(0);
        __builtin_amdgcn_sched_barrier(0);

        // ---- phase 1: publish S1(t); MFMA(m2,m3 x bCur); read bNxt,aLo2(S1)
        if (more) {
            asm volatile("s_waitcnt vmcnt(2)" ::: "memory");
        } else {
            asm volatile("s_waitcnt vmcnt(0)" ::: "memory");
        }
        __builtin_amdgcn_s_barrier();
        __builtin_amdgcn_sched_barrier(0);
#pragma unroll
        for (int nt = 0; nt < 2; ++nt)
#pragma unroll
            for (int kk = 0; kk < 2; ++kk)
                bNxt[nt * 2 + kk] = *(const bf16x8*)(S1 + boffs[nt][kk]);
#pragma unroll
        for (int mt = 0; mt < 2; ++mt)
#pragma unroll
            for (int kk = 0; kk < 2; ++kk)
                aLo2[mt * 2 + kk] = *(const bf16x8*)(S1 + aoffs[mt][kk]);
        if (more) stageB(t + 1, 0, d0);
        __builtin_amdgcn_sched_barrier(0);
        __builtin_amdgcn_s_setprio(1);
#pragma unroll
        for (int kk = 0; kk < 2; ++kk)
#pragma unroll
            for (int mt = 0; mt < 2; ++mt)
#pragma unroll
                for (int nt = 0; nt < 2; ++nt)
                    acc[2 + mt][nt] = __builtin_amdgcn_mfma_f32_32x32x16_bf16(
                        aHi[mt * 2 + kk], bCur[nt * 2 + kk], acc[2 + mt][nt], 0, 0, 0);
        __builtin_amdgcn_s_setprio(0);
        __builtin_amdgcn_sched_barrier(0);

        // ---- phase 2: MFMA(m0,m1 x bNxt); read-ahead aHi2(S1); stage A(t+1,1)
#pragma unroll
        for (int mt = 0; mt < 2; ++mt)
#pragma unroll
            for (int kk = 0; kk < 2; ++kk)
                aHi2[mt * 2 + kk] = *(const bf16x8*)(S1 + aoffs[2 + mt][kk]);
        if (more) stageA(t + 1, 1, d1);
        __builtin_amdgcn_sched_barrier(0);
        __builtin_amdgcn_s_setprio(1);
#pragma unroll
        for (int kk = 0; kk < 2; ++kk)
#pragma unroll
            for (int mt = 0; mt < 2; ++mt)
#pragma unroll
                for (int nt = 0; nt < 2; ++nt)
                    acc[mt][nt] = __builtin_amdgcn_mfma_f32_32x32x16_bf16(
                        aLo2[mt * 2 + kk], bNxt[nt * 2 + kk], acc[mt][nt], 0, 0, 0);
        __builtin_amdgcn_s_setprio(0);
        __builtin_amdgcn_sched_barrier(0);

        // ---- phase 3: publish S0(t+1); MFMA(m2,m3 x bNxt); read bCur,aLo(Sn)
        if (more) {
            asm volatile("s_waitcnt vmcnt(2)" ::: "memory");
            __builtin_amdgcn_s_barrier();
            __builtin_amdgcn_sched_barrier(0);
#pragma unroll
            for (int nt = 0; nt < 2; ++nt)
#pragma unroll
                for (int kk = 0; kk < 2; ++kk)
                    bCur[nt * 2 + kk] = *(const bf16x8*)(Sn + boffs[nt][kk]);
#pragma unroll
            for (int mt = 0; mt < 2; ++mt)
#pragma unroll
                for (int kk = 0; kk < 2; ++kk)
                    aLo[mt * 2 + kk] = *(const bf16x8*)(Sn + aoffs[mt][kk]);
            stageB(t + 1, 1, d1);
        }
        __builtin_amdgcn_sched_barrier(0);
        __builtin_amdgcn_s_setprio(1);
#pragma unroll
        for (int kk = 0; kk < 2; ++kk)
#pragma unroll
            for (int mt = 0; mt < 2; ++mt)
#pragma unroll
                for (int nt = 0; nt < 2; ++nt)
                    acc[2 + mt][nt] = __builtin_amdgcn_mfma_f32_32x32x16_bf16(
                        aHi2[mt * 2 + kk], bNxt[nt * 2 + kk], acc[2 + mt][nt], 0, 0, 0);
        __builtin_amdgcn_s_setprio(0);
        __builtin_amdgcn_sched_barrier(0);
    }

    // epilogue: C/D map col = l&31, row = (reg&3) + 8*(reg>>2) + 4*(l>>5)
#pragma unroll
    for (int mt = 0; mt < 4; ++mt) {
#pragma unroll
        for (int nt = 0; nt < 2; ++nt) {
            const int colg = colBase + wn * 64 + nt * 32 + r32;
            const int rbase = rowBase + wm * 128 + mt * 32 + 4 * h32;
#pragma unroll
            for (int reg = 0; reg < 16; ++reg) {
                const int rowg = rbase + (reg & 3) + 8 * (reg >> 2);
                C[(size_t)rowg * DOUT + colg] = acc[mt][nt][reg];
            }
        }
    }
}

// ---------------------------------------------------------------------------
extern "C" void kernel_launch(void* const* d_in, const int* in_sizes, int n_in,
                              void* d_out, int out_size, void* d_ws, size_t ws_size,
                              hipStream_t stream) {
    const float* x      = (const float*)d_in[0];
    const int*   codes  = (const int*)d_in[1];
    const float* absmax = (const float*)d_in[2];
    const float* bias   = (const float*)d_in[3];
    const float* lora_A = (const float*)d_in[4];
    const float* lora_B = (const float*)d_in[5];
    float* out = (float*)d_out;

    unsigned short* xe = (unsigned short*)d_ws;        // [TOK][KE] bf16
    unsigned short* we = xe + (size_t)TOK * KE;        // [DOUT][KE] bf16

    prep_fused<<<PXB + DQB + TLB, 256, 0, stream>>>(x, lora_A, codes, absmax,
                                                    bias, lora_B, xe, we);
    gemm_bt<<<(TOK / BM) * (DOUT / BN), 512, 0, stream>>>(xe, we, out);
}